// Round 12
// baseline (91.120 us; speedup 1.0000x reference)
//
#include <hip/hip_runtime.h>
#include <hip/hip_bf16.h>

#define NCH      256
#define NNB      262144
#define BN       128            // dtile columns (2 MFMA tiles)
#define NDT      (NNB / BN)     // 2048 dtiles
#define NB       256            // K1 grid: 1 block per CU
#define DTPB     (NDT / NB)     // 8 dtiles per block
#define NENT     (NCH * 6)
#define NTHREADS 512

typedef __bf16        bf16x8 __attribute__((ext_vector_type(8)));
typedef float         f32x4  __attribute__((ext_vector_type(4)));
typedef float         f32x2  __attribute__((ext_vector_type(2)));
typedef unsigned int  u32x4  __attribute__((ext_vector_type(4)));
typedef unsigned int  u32x2  __attribute__((ext_vector_type(2)));
typedef short         v4s    __attribute__((ext_vector_type(4)));

union FragU  { u32x4 u; bf16x8 b; };
union Frag2U { u32x2 u; v4s    s; };

__device__ __forceinline__ unsigned pk2(float lo, float hi) {
    union { __hip_bfloat162 h2; unsigned u; } cv;
    cv.h2 = __float22bfloat162_rn(make_float2(lo, hi));
    return cv.u;
}

__device__ __forceinline__ const float* uni_ptr(const float* p) {
    unsigned long long u = (unsigned long long)p;
    unsigned lo = __builtin_amdgcn_readfirstlane((unsigned)u);
    unsigned hi = __builtin_amdgcn_readfirstlane((unsigned)(u >> 32));
    return (const float*)(((unsigned long long)hi << 32) | lo);
}

// raw barrier: LDS writes visible, global loads stay in flight (no vmcnt drain)
#define LBAR() do {                                                  \
    asm volatile("s_waitcnt lgkmcnt(0)" ::: "memory");               \
    __builtin_amdgcn_sched_barrier(0);                               \
    __builtin_amdgcn_s_barrier();                                    \
    __builtin_amdgcn_sched_barrier(0);                               \
} while (0)

// one 16-col compute block: GEMM1 (2 MFMAs per ds_read_b128) + radial + GEMM2
// Swizzle is pair-granular: ((col>>1)&7)<<4; for reads col = colb + il,
// colb = CB*16 -> sw = ((il>>1)&7)<<4 (lane-only).
#define CBODY(CB)                                                                  \
{                                                                                  \
    const int colb = (CB) * 16;                                                    \
    Frag2U gf;                                                                     \
    gf.u = *(const u32x2*)(gTP +                                                   \
           (((unsigned)(il * 256 + (colb + q * 4) * 2)) ^                          \
            (((unsigned)(il & 7)) << 3)));                                         \
    f32x4 hp0 = {0.f, 0.f, 0.f, 0.f}, hp1 = {0.f, 0.f, 0.f, 0.f};                  \
    const unsigned rb = (unsigned)((colb + il) * 512);                             \
    _Pragma("unroll")                                                              \
    for (int jb = 0; jb < 8; ++jb) {                                               \
        FragU f0;                                                                  \
        f0.u = *(const u32x4*)((const char*)htP +                                  \
               ((rb + (unsigned)(jb * 64 + q * 16)) ^ sw));                        \
        hp0 = __builtin_amdgcn_mfma_f32_16x16x32_bf16(f0.b, wf[0][jb].b, hp0, 0, 0, 0); \
        hp1 = __builtin_amdgcn_mfma_f32_16x16x32_bf16(f0.b, wf[1][jb].b, hp1, 0, 0, 0); \
    }                                                                              \
    f32x4 d4 = *(const f32x4*)(dtP + colb + q * 4);                                \
    f32x4 i4 = *(const f32x4*)(dtP + BN + colb + q * 4);                           \
    Frag2U a0, a1;                                                                 \
    {                                                                              \
        float m0 = __sinf(fk0 * d4[0]) * i4[0] * hp0[0];                           \
        float m1 = __sinf(fk0 * d4[1]) * i4[1] * hp0[1];                           \
        float m2 = __sinf(fk0 * d4[2]) * i4[2] * hp0[2];                           \
        float m3 = __sinf(fk0 * d4[3]) * i4[3] * hp0[3];                           \
        a0.u[0] = pk2(m0, m1); a0.u[1] = pk2(m2, m3);                              \
        float n0 = __sinf(fk1 * d4[0]) * i4[0] * hp1[0];                           \
        float n1 = __sinf(fk1 * d4[1]) * i4[1] * hp1[1];                           \
        float n2 = __sinf(fk1 * d4[2]) * i4[2] * hp1[2];                           \
        float n3 = __sinf(fk1 * d4[3]) * i4[3] * hp1[3];                           \
        a1.u[0] = pk2(n0, n1); a1.u[1] = pk2(n2, n3);                              \
    }                                                                              \
    acc0 = __builtin_amdgcn_mfma_f32_16x16x16bf16_1k(a0.s, gf.s, acc0, 0, 0, 0);   \
    acc1 = __builtin_amdgcn_mfma_f32_16x16x16bf16_1k(a1.s, gf.s, acc1, 0, 0, 0);   \
}

// issue 4-row chunk Q of next dtile: 1 dwordx2 per row (lane covers cols 2c,2c+1)
// -> per wave-instr: 64 lanes x 8B = one full 512B contiguous row. THE granule test.
#define CHUNK4_ISSUE(Q)                                                            \
    if (hasNext) {                                                                 \
        _Pragma("unroll")                                                          \
        for (int j2 = 0; j2 < 4; ++j2)                                             \
            hc[j2] = *(const f32x2*)(hwb + (size_t)((Q) * 4 + j2) * NNB            \
                                         + baseN + sc0);                           \
    }

// pack chunk Q: 4 j's of col 2c and col 2c+1 -> two ds_write_b64
#define CHUNK4_PACK(Q)                                                             \
    if (hasNext) {                                                                 \
        u32x2 wx, wy;                                                              \
        wx[0] = pk2(hc[0][0], hc[1][0]); wx[1] = pk2(hc[2][0], hc[3][0]);          \
        wy[0] = pk2(hc[0][1], hc[1][1]); wy[1] = pk2(hc[2][1], hc[3][1]);          \
        const unsigned jo = (unsigned)(wave * 64 + (Q) * 8);                       \
        *(u32x2*)((char*)htN + (((unsigned)(sc0 * 512)       + jo) ^ swp)) = wx;   \
        *(u32x2*)((char*)htN + (((unsigned)(sc0 * 512 + 512) + jo) ^ swp)) = wy;   \
    }

// geometry (d, invd, G table) for 128 cols into buf B from regs gx,gy,gz (t<128)
#define GEOM(B)                                                                    \
    if (t < 128) {                                                                 \
        float dd = sqrtf(gx * gx + gy * gy + gz * gz);                             \
        float iv = 1.0f / dd;                                                      \
        dtab[B][0][t] = dd; dtab[B][1][t] = iv;                                    \
        float i2 = iv * iv;                                                        \
        float gg[6] = { gx * gx * i2, gx * gy * i2, gx * gz * i2,                  \
                        gy * gy * i2, gy * gz * i2, gz * gz * i2 };                \
        _Pragma("unroll")                                                          \
        for (int de = 0; de < 6; ++de) {                                           \
            unsigned off = ((unsigned)(de * 256 + t * 2)) ^ (((unsigned)de) << 3); \
            *(unsigned short*)((char*)gT[B] + off) =                               \
                (unsigned short)(pk2(gg[de], 0.f) & 0xffffu);                      \
        }                                                                          \
    }

// K1: 512 threads = 8 waves, 1 block/CU (LDS 138 KB -> VGPR budget 128, R9-verified).
// dtile = 128 cols. Staging: wave stages rows [w*32,+32), 1 dwordx2-instr per row
// = 512B contiguous DRAM burst (vs 256B in R8/R11 - the granularity experiment).
// Compute: wave owns k [w*32,+32) over 128 cols; ds_read_b128 feeds 2 MFMAs.
// Register discipline (R11): 4-row chunks (8 f32 live), one per CBODY slot;
// geometry on t<128 only. Peak live ~120 <= 128.
// ws layout: [block][entry = k*6 + m6]
__global__ __launch_bounds__(NTHREADS, 1) void create_As_k1(
        const float* __restrict__ h, const float* __restrict__ rp,
        const float* __restrict__ W, float* __restrict__ ws)
{
    __shared__ unsigned short htile[2][BN * NCH];        // 2 x 64 KB [col][j], ^(((col>>1)&7)<<4)
    __shared__ unsigned short gT[2][16 * BN];            // 2 x 4 KB [de][col], ^((de&7)<<3)
    __shared__ __align__(16) float dtab[2][2][BN];       // [p][{d,invd}][col]

    const int t    = threadIdx.x;
    const int wave = t >> 6;        // 0..7
    const int il   = t & 15;
    const int q    = (t >> 4) & 3;
    const int c    = t & 63;
    const int k0   = wave * 32;
    const int sc0  = 2 * c;                            // staged col pair {sc0, sc0+1}
    const unsigned sw  = ((unsigned)((il >> 1) & 7)) << 4;  // read-side swizzle
    const unsigned swp = ((unsigned)(c & 7)) << 4;          // write-side ((sc0>>1)&7)<<4
    const float fk0 = (float)(k0 + il + 1);
    const float fk1 = fk0 + 16.0f;

    // zero gT (rows 6..15 must stay zero): 2048 u32, 512 threads x 4
    #pragma unroll
    for (int z = 0; z < 4; ++z) ((unsigned*)gT)[t + z * NTHREADS] = 0u;

    // W fragments: lane holds W[k0 + kt*16 + il][jb*32 + q*8 + e]  (64 VGPR resident)
    FragU wf[2][8];
    #pragma unroll
    for (int kt = 0; kt < 2; ++kt) {
        const float* wr = W + (size_t)(k0 + kt * 16 + il) * NCH + q * 8;
        #pragma unroll
        for (int jb = 0; jb < 8; ++jb) {
            f32x4 a = *(const f32x4*)(wr + jb * 32);
            f32x4 b = *(const f32x4*)(wr + jb * 32 + 4);
            wf[kt][jb].u[0] = pk2(a[0], a[1]);
            wf[kt][jb].u[1] = pk2(a[2], a[3]);
            wf[kt][jb].u[2] = pk2(b[0], b[1]);
            wf[kt][jb].u[3] = pk2(b[2], b[3]);
        }
    }

    f32x4 acc0 = {0.f, 0.f, 0.f, 0.f};
    f32x4 acc1 = {0.f, 0.f, 0.f, 0.f};

    // staging row base: wave stages rows [wave*32, +32)
    const float* hwb = uni_ptr(h + (size_t)(wave * 32) * NNB);

    const int d0 = blockIdx.x;

    __syncthreads();   // gT zero-init visible before prologue writes

    // -------- prologue: stage dtile d0 into buf 0; geometry d0 (t<128) --------
    {
        const unsigned base = (unsigned)(d0 * BN);
        #pragma unroll
        for (int qq = 0; qq < 8; ++qq) {
            f32x2 hv[4];
            #pragma unroll
            for (int j2 = 0; j2 < 4; ++j2)
                hv[j2] = *(const f32x2*)(hwb + (size_t)(qq * 4 + j2) * NNB + base + sc0);
            u32x2 wx, wy;
            wx[0] = pk2(hv[0][0], hv[1][0]); wx[1] = pk2(hv[2][0], hv[3][0]);
            wy[0] = pk2(hv[0][1], hv[1][1]); wy[1] = pk2(hv[2][1], hv[3][1]);
            const unsigned jo = (unsigned)(wave * 64 + qq * 8);
            *(u32x2*)((char*)htile[0] + (((unsigned)(sc0 * 512)       + jo) ^ swp)) = wx;
            *(u32x2*)((char*)htile[0] + (((unsigned)(sc0 * 512 + 512) + jo) ^ swp)) = wy;
        }
        if (t < 128) {
            const unsigned ii = base + (unsigned)t;
            float gx = rp[ii], gy = rp[(size_t)NNB + ii], gz = rp[2 * (size_t)NNB + ii];
            GEOM(0)
        }
    }
    LBAR();

    #pragma unroll 1
    for (int it = 0; it < DTPB; ++it) {
        const int P = it & 1;
        const unsigned short* htP = htile[P];
        unsigned short*       htN = htile[P ^ 1];
        const char*  gTP = (const char*)gT[P];
        const float* dtP = &dtab[P][0][0];
        const bool hasNext = (it + 1 < DTPB);
        const unsigned baseN = (unsigned)((d0 + (it + 1) * NB) * BN);

        // geometry rp for next dtile: t<128 only, issued early, consumed at end
        float gx = 0.f, gy = 0.f, gz = 0.f;
        if (hasNext && t < 128) {
            const unsigned ii = baseN + (unsigned)t;
            gx = rp[ii]; gy = rp[(size_t)NNB + ii]; gz = rp[2 * (size_t)NNB + ii];
        }

        f32x2 hc[4];
        CHUNK4_ISSUE(0)
        __builtin_amdgcn_sched_barrier(0);
        CBODY(0)
        __builtin_amdgcn_sched_barrier(0);
        CHUNK4_PACK(0) CHUNK4_ISSUE(1)
        __builtin_amdgcn_sched_barrier(0);
        CBODY(1)
        __builtin_amdgcn_sched_barrier(0);
        CHUNK4_PACK(1) CHUNK4_ISSUE(2)
        __builtin_amdgcn_sched_barrier(0);
        CBODY(2)
        __builtin_amdgcn_sched_barrier(0);
        CHUNK4_PACK(2) CHUNK4_ISSUE(3)
        __builtin_amdgcn_sched_barrier(0);
        CBODY(3)
        __builtin_amdgcn_sched_barrier(0);
        CHUNK4_PACK(3) CHUNK4_ISSUE(4)
        __builtin_amdgcn_sched_barrier(0);
        CBODY(4)
        __builtin_amdgcn_sched_barrier(0);
        CHUNK4_PACK(4) CHUNK4_ISSUE(5)
        __builtin_amdgcn_sched_barrier(0);
        CBODY(5)
        __builtin_amdgcn_sched_barrier(0);
        CHUNK4_PACK(5) CHUNK4_ISSUE(6)
        __builtin_amdgcn_sched_barrier(0);
        CBODY(6)
        __builtin_amdgcn_sched_barrier(0);
        CHUNK4_PACK(6) CHUNK4_ISSUE(7)
        __builtin_amdgcn_sched_barrier(0);
        CBODY(7)
        __builtin_amdgcn_sched_barrier(0);
        CHUNK4_PACK(7)
        if (hasNext) { GEOM(P ^ 1) }
        LBAR();
    }

    // ---- store: lane holds A[k = k0 + q*4 + r (+16)][de = il] ----
    if (il < 6) {
        float* dst = ws + (size_t)blockIdx.x * NENT;
        #pragma unroll
        for (int r = 0; r < 4; ++r) {
            dst[(k0 + q * 4 + r) * 6 + il]      = acc0[r];
            dst[(k0 + 16 + q * 4 + r) * 6 + il] = acc1[r];
        }
    }
}

// K2: 24 blocks x 512. Block eb owns entries [eb*64, +64); coalesced rows; LDS reduce.
__global__ void create_As_k2(const float* __restrict__ ws, float* __restrict__ out)
{
    __shared__ float red[8][64];
    const int eb = blockIdx.x;
    const int w  = threadIdx.x >> 6;
    const int l  = threadIdx.x & 63;
    float s = 0.f;
    #pragma unroll 4
    for (int b = w; b < NB; b += 8)
        s += ws[(size_t)b * NENT + (unsigned)(eb * 64 + l)];
    red[w][l] = s;
    __syncthreads();
    if (w == 0) {
        float v = red[0][l] + red[1][l] + red[2][l] + red[3][l]
                + red[4][l] + red[5][l] + red[6][l] + red[7][l];
        const int e  = eb * 64 + l;
        const int k  = e / 6;
        const int m6 = e - k * 6;
        const int d  = (m6 < 3) ? 0 : ((m6 < 5) ? 1 : 2);
        const int e2 = (m6 < 3) ? m6 : ((m6 < 5) ? (m6 - 2) : 2);
        out[k * 9 + d * 3 + e2] = v;
        if (d != e2) out[k * 9 + e2 * 3 + d] = v;
    }
}

extern "C" void kernel_launch(void* const* d_in, const int* in_sizes, int n_in,
                              void* d_out, int out_size, void* d_ws, size_t ws_size,
                              hipStream_t stream)
{
    const float* h  = (const float*)d_in[0];
    const float* rp = (const float*)d_in[1];
    const float* W  = (const float*)d_in[2];
    float* out = (float*)d_out;
    float* ws  = (float*)d_ws;

    hipLaunchKernelGGL(create_As_k1, dim3(NB), dim3(NTHREADS), 0, stream, h, rp, W, ws);
    hipLaunchKernelGGL(create_As_k2, dim3(NENT / 64), dim3(512), 0, stream, ws, out);
}